// Round 10
// baseline (424.716 us; speedup 1.0000x reference)
//
#include <hip/hip_runtime.h>
#include <hip/hip_cooperative_groups.h>

namespace cg = cooperative_groups;

// ---------------------------------------------------------------------------
// GCN 2-layer forward on MI355X.
//  out = Ahat( relu( Ahat (X W1) + b1 ) W2 ) + b2,  Ahat = D^-1/2 (A+I) D^-1/2
// R10: entire CSR build + weight conversion fused into ONE cooperative kernel
//      (grid.sync between phases) -> 12 kernels become 5. agg/gemm from R9
//      (quarter-wave agg, reg-prefetch MFMA gemms) unchanged - they sit at
//      their traffic floors (agg1: 8 XCD x 25.6MB @ ~3.4TB/s fabric ceiling).
// ---------------------------------------------------------------------------

constexpr int IN_CH  = 256;
constexpr int HID    = 128;
constexpr int OUT_CH = 64;
constexpr int EPB = 4096;         // edges per block in hist/scatter

typedef __attribute__((ext_vector_type(8))) short short8;
typedef __attribute__((ext_vector_type(4))) float f32x4;

union F8 {                       // one MFMA A/B fragment: 8 bf16
    short8 v;
    unsigned short u[8];
    uint4  q;
};

// ---- bf16 helpers (RNE) ----
__device__ inline unsigned short f2b(float f) {
    unsigned u = __float_as_uint(f);
    u += 0x7fffu + ((u >> 16) & 1u);
    return (unsigned short)(u >> 16);
}
__device__ inline unsigned pack_bf16(float a, float b) {
    unsigned ua = __float_as_uint(a); ua += 0x7fffu + ((ua >> 16) & 1u);
    unsigned ub = __float_as_uint(b); ub += 0x7fffu + ((ub >> 16) & 1u);
    return (ua >> 16) | (ub & 0xffff0000u);
}
__device__ inline float2 unpack_bf16(unsigned v) {
    return make_float2(__uint_as_float(v << 16), __uint_as_float(v & 0xffff0000u));
}

// ---------------- Fused CSR build + weight convert (cooperative) -------------
// Phases: P0 wt convert (no sync needed) ; P1 LDS hist + lrank ; P2 scan
// (rowsum -> redundant 512-slot scan -> per-row scan) ; P3 scatter ;
// P4 per-bucket finalize (row_ptr, dis, node-sorted csr). LDS atomics only.

__global__ __launch_bounds__(256) void csr_coop(
    const int* __restrict__ src, const int* __restrict__ dst,
    unsigned short* __restrict__ lrank, int* __restrict__ blockhist,
    int* __restrict__ rowsum, int* __restrict__ flatscan,
    unsigned* __restrict__ sorted, int* __restrict__ csr_src,
    int* __restrict__ row_ptr, float* __restrict__ dis,
    const float* __restrict__ W1, unsigned short* __restrict__ wt1,
    const float* __restrict__ W2, unsigned short* __restrict__ wt2,
    int E, int n, int NB, int NBUCK, int L) {
    cg::grid_group grid = cg::this_grid();
    __shared__ int smem[1024];
    int t = threadIdx.x, b = blockIdx.x, G = gridDim.x;

    // ---- P0: weight transpose + bf16 convert (independent of P1..P4) ----
    constexpr int NWT1 = IN_CH * HID;      // 32768
    constexpr int NWT2 = HID * OUT_CH;     // 8192
    for (int i = b * 256 + t; i < NWT1 + NWT2; i += G * 256) {
        if (i < NWT1) {
            int c = i >> 8, k = i & 255;               // wt1[c*256+k] = W1[k][c]
            wt1[i] = f2b(W1[k * HID + c]);
        } else {
            int j = i - NWT1;
            int c = j >> 7, k = j & 127;               // wt2[c*128+k] = W2[k][c]
            wt2[j] = f2b(W2[k * OUT_CH + c]);
        }
    }

    // ---- P1: per-block 512-bin histogram + local rank ----
    smem[t] = 0; smem[t + 256] = 0;
    __syncthreads();
    if (b < NB) {
        int base = b * EPB;
        #pragma unroll 4
        for (int j = 0; j < EPB / 256; ++j) {
            int e = base + j * 256 + t;
            if (e < E) {
                int bk = ((unsigned)dst[e]) >> 8;
                lrank[e] = (unsigned short)atomicAdd(&smem[bk], 1);
            }
        }
        __syncthreads();
        for (int l = t; l < NBUCK; l += 256)
            blockhist[l * NB + b] = smem[l];           // bucket-major
    }
    grid.sync();

    // ---- P2a: per-bucket row totals ----
    if (b < NBUCK) {
        int s = 0;
        for (int k = t; k < NB; k += 256) s += blockhist[b * NB + k];
        smem[t] = s;
        __syncthreads();
        for (int ofs = 128; ofs > 0; ofs >>= 1) {
            if (t < ofs) smem[t] += smem[t + ofs];
            __syncthreads();
        }
        if (t == 0) rowsum[b] = smem[0];
    }
    grid.sync();

    // ---- P2b: redundant inclusive scan of rowsum[0..NBUCK) (512 slots) ----
    {
        int v0 = (t < NBUCK) ? rowsum[t] : 0;
        int v1 = (t + 256 < NBUCK) ? rowsum[t + 256] : 0;
        smem[t] = v0; smem[t + 256] = v1;
        __syncthreads();
        for (int ofs = 1; ofs < 512; ofs <<= 1) {
            int a0 = (t >= ofs) ? smem[t - ofs] : 0;
            int a1 = (t + 256 >= ofs) ? smem[t + 256 - ofs] : 0;
            __syncthreads();
            smem[t] += a0; smem[t + 256] += a1;
            __syncthreads();
        }
        if (b == 0 && t == 0) flatscan[L] = smem[511];     // grand total == E
    }
    int bucketbase = (b == 0 || b >= NBUCK) ? 0 : smem[b - 1];  // exclusive base
    __syncthreads();

    // ---- P2c: per-bucket row scan -> flatscan ----
    if (b < NBUCK) {
        int v0 = (t < NB) ? blockhist[b * NB + t] : 0;
        int v1 = (t + 256 < NB) ? blockhist[b * NB + t + 256] : 0;
        smem[t] = v0; smem[t + 256] = v1;
        __syncthreads();
        for (int ofs = 1; ofs < 512; ofs <<= 1) {
            int a0 = (t >= ofs) ? smem[t - ofs] : 0;
            int a1 = (t + 256 >= ofs) ? smem[t + 256 - ofs] : 0;
            __syncthreads();
            smem[t] += a0; smem[t + 256] += a1;
            __syncthreads();
        }
        if (t < NB)       flatscan[b * NB + t]       = bucketbase + smem[t] - v0;
        if (t + 256 < NB) flatscan[b * NB + t + 256] = bucketbase + smem[t + 256] - v1;
    }
    grid.sync();

    // ---- P3: scatter edges into bucket-sorted order ----
    if (b < NB) {
        int base = b * EPB;
        #pragma unroll 4
        for (int j = 0; j < EPB / 256; ++j) {
            int e = base + j * 256 + t;
            if (e < E) {
                int d = dst[e];
                int bk = ((unsigned)d) >> 8;
                int slot = flatscan[bk * NB + b] + (int)lrank[e];
                sorted[slot] = (((unsigned)(d & 255)) << 24) | (unsigned)src[e];
            }
        }
    }
    grid.sync();

    // ---- P4: per-bucket finalize: counts, scan, row_ptr, dis, csr place ----
    if (b < NBUCK) {
        int ebeg = flatscan[b * NB];
        int eend = flatscan[(b + 1) * NB];      // b=NBUCK-1 -> flatscan[L]=E
        smem[t] = 0;
        __syncthreads();
        for (int e = ebeg + t; e < eend; e += 256)
            atomicAdd(&smem[sorted[e] >> 24], 1);
        __syncthreads();
        int v = smem[t];
        smem[256 + t] = v;
        __syncthreads();
        for (int ofs = 1; ofs < 256; ofs <<= 1) {
            int tv = (t >= ofs) ? smem[256 + t - ofs] : 0;
            __syncthreads();
            smem[256 + t] += tv;
            __syncthreads();
        }
        int excl = smem[256 + t] - v;
        int node = b * 256 + t;
        if (node <= n) row_ptr[node] = ebeg + excl;
        if (node < n)  dis[node] = rsqrtf(1.0f + (float)v);
        smem[512 + t] = excl;
        __syncthreads();
        for (int e = ebeg + t; e < eend; e += 256) {
            unsigned s = sorted[e];
            int pos = atomicAdd(&smem[512 + (s >> 24)], 1);
            csr_src[ebeg + pos] = (int)(s & 0xFFFFFFu);
        }
    }
}

// ---------------- GEMM 1 (MFMA + LDS + reg prefetch) -------------------------

__global__ __launch_bounds__(512) void gemm1_mfma(
    const float* __restrict__ X, const unsigned short* __restrict__ Wt,
    const float* __restrict__ dis, unsigned short* __restrict__ G, int n) {
    constexpr int K = 256, LP = 20, NS = 8;
    __shared__ unsigned xs[2][256 * LP];          // 2 x 20KB

    int tid  = threadIdx.x;
    int lane = tid & 63;
    int w    = tid >> 6;
    int wm = w >> 1, wn = w & 1;
    int rowbase = blockIdx.x * 256 + wm * 64;
    int colbase = wn * 64;
    int la = lane & 15, lb = lane >> 4;

    int srow = tid >> 1, shalf = tid & 1;
    int grow = blockIdx.x * 256 + srow;
    if (grow >= n) grow = n - 1;
    const float* xrow = X + (size_t)grow * K + shalf * 16;
    int sofs = srow * LP + shalf * 8;             // uint offset in xs

    float4 pf0, pf1, pf2, pf3;
    #define G1_LOAD(ks) { const float* p_ = xrow + (ks) * 32;                 \
        pf0 = *(const float4*)(p_);     pf1 = *(const float4*)(p_ + 4);       \
        pf2 = *(const float4*)(p_ + 8); pf3 = *(const float4*)(p_ + 12); }
    #define G1_WRITE(buf) { uint4 o_;                                         \
        o_.x = pack_bf16(pf0.x, pf0.y); o_.y = pack_bf16(pf0.z, pf0.w);       \
        o_.z = pack_bf16(pf1.x, pf1.y); o_.w = pack_bf16(pf1.z, pf1.w);       \
        *(uint4*)&xs[buf][sofs] = o_;                                         \
        o_.x = pack_bf16(pf2.x, pf2.y); o_.y = pack_bf16(pf2.z, pf2.w);       \
        o_.z = pack_bf16(pf3.x, pf3.y); o_.w = pack_bf16(pf3.z, pf3.w);       \
        *(uint4*)&xs[buf][sofs + 4] = o_; }

    f32x4 acc[4][4];
    #pragma unroll
    for (int m = 0; m < 4; ++m)
        #pragma unroll
        for (int nn = 0; nn < 4; ++nn) acc[m][nn] = (f32x4){0.f, 0.f, 0.f, 0.f};

    G1_LOAD(0);
    G1_WRITE(0);
    G1_LOAD(1);
    __syncthreads();

    #pragma unroll
    for (int ks = 0; ks < NS; ++ks) {
        int cur = ks & 1;
        if (ks + 1 < NS) G1_WRITE(cur ^ 1);       // regs hold slab ks+1
        if (ks + 2 < NS) G1_LOAD(ks + 2);         // issue early, consume next step
        F8 a[4], b[4];
        #pragma unroll
        for (int m = 0; m < 4; ++m)
            a[m].q = *(const uint4*)&xs[cur][(wm * 64 + m * 16 + la) * LP + lb * 4];
        #pragma unroll
        for (int nn = 0; nn < 4; ++nn) {
            int col = colbase + nn * 16 + la;
            b[nn].q = *(const uint4*)(Wt + (size_t)col * K + ks * 32 + lb * 8);
        }
        #pragma unroll
        for (int m = 0; m < 4; ++m)
            #pragma unroll
            for (int nn = 0; nn < 4; ++nn)
                acc[m][nn] = __builtin_amdgcn_mfma_f32_16x16x32_bf16(
                    a[m].v, b[nn].v, acc[m][nn], 0, 0, 0);
        __syncthreads();
    }
    #undef G1_LOAD
    #undef G1_WRITE

    #pragma unroll
    for (int m = 0; m < 4; ++m) {
        int r0 = rowbase + m * 16 + lb * 4;
        float dv[4];
        #pragma unroll
        for (int r = 0; r < 4; ++r) dv[r] = (r0 + r < n) ? dis[r0 + r] : 0.f;
        #pragma unroll
        for (int nn = 0; nn < 4; ++nn) {
            int col = colbase + nn * 16 + la;
            #pragma unroll
            for (int r = 0; r < 4; ++r) {
                int row = r0 + r;
                if (row < n)
                    G[(size_t)row * HID + col] = f2b(acc[m][nn][r] * dv[r]);
            }
        }
    }
}

// ---------------- GEMM 2 (MFMA + LDS + reg prefetch) -------------------------

__global__ __launch_bounds__(512) void gemm2_mfma(
    const unsigned short* __restrict__ H, const unsigned short* __restrict__ Wt,
    const float* __restrict__ dis, unsigned short* __restrict__ G, int n) {
    constexpr int K = 128, LP = 20, NS = 4;
    __shared__ unsigned xs[2][256 * LP];

    int tid  = threadIdx.x;
    int lane = tid & 63;
    int w    = tid >> 6;
    int wm = w >> 1, wn = w & 1;
    int rowbase = blockIdx.x * 256 + wm * 64;
    int colbase = wn * 32;
    int la = lane & 15, lb = lane >> 4;

    const unsigned* Hu = (const unsigned*)H;      // 64 uints per row

    int sr0 = tid >> 2, sq0 = tid & 3;
    int sr1 = (tid + 512) >> 2, sq1 = tid & 3;
    int g0 = blockIdx.x * 256 + sr0; g0 = g0 < n ? g0 : n - 1;
    int g1 = blockIdx.x * 256 + sr1; g1 = g1 < n ? g1 : n - 1;

    uint4 pf0, pf1;
    #define G2_LOAD(ks) {                                                     \
        pf0 = *(const uint4*)&Hu[(size_t)g0 * 64 + (ks) * 16 + sq0 * 4];      \
        pf1 = *(const uint4*)&Hu[(size_t)g1 * 64 + (ks) * 16 + sq1 * 4]; }
    #define G2_WRITE(buf) {                                                   \
        *(uint4*)&xs[buf][sr0 * LP + sq0 * 4] = pf0;                          \
        *(uint4*)&xs[buf][sr1 * LP + sq1 * 4] = pf1; }

    f32x4 acc[4][2];
    #pragma unroll
    for (int m = 0; m < 4; ++m)
        #pragma unroll
        for (int nn = 0; nn < 2; ++nn) acc[m][nn] = (f32x4){0.f, 0.f, 0.f, 0.f};

    G2_LOAD(0);
    G2_WRITE(0);
    G2_LOAD(1);
    __syncthreads();

    #pragma unroll
    for (int ks = 0; ks < NS; ++ks) {
        int cur = ks & 1;
        if (ks + 1 < NS) G2_WRITE(cur ^ 1);
        if (ks + 2 < NS) G2_LOAD(ks + 2);
        F8 a[4], b[2];
        #pragma unroll
        for (int m = 0; m < 4; ++m)
            a[m].q = *(const uint4*)&xs[cur][(wm * 64 + m * 16 + la) * LP + lb * 4];
        #pragma unroll
        for (int nn = 0; nn < 2; ++nn) {
            int col = colbase + nn * 16 + la;
            b[nn].q = *(const uint4*)(Wt + (size_t)col * K + ks * 32 + lb * 8);
        }
        #pragma unroll
        for (int m = 0; m < 4; ++m)
            #pragma unroll
            for (int nn = 0; nn < 2; ++nn)
                acc[m][nn] = __builtin_amdgcn_mfma_f32_16x16x32_bf16(
                    a[m].v, b[nn].v, acc[m][nn], 0, 0, 0);
        __syncthreads();
    }
    #undef G2_LOAD
    #undef G2_WRITE

    #pragma unroll
    for (int m = 0; m < 4; ++m) {
        int r0 = rowbase + m * 16 + lb * 4;
        float dv[4];
        #pragma unroll
        for (int r = 0; r < 4; ++r) dv[r] = (r0 + r < n) ? dis[r0 + r] : 0.f;
        #pragma unroll
        for (int nn = 0; nn < 2; ++nn) {
            int col = colbase + nn * 16 + la;
            #pragma unroll
            for (int r = 0; r < 4; ++r) {
                int row = r0 + r;
                if (row < n)
                    G[(size_t)row * OUT_CH + col] = f2b(acc[m][nn][r] * dv[r]);
            }
        }
    }
}

// ---------------- Aggregation 1: h1 = bf16(relu(dis .* (self+gather) + b1)) --
// Quarter-wave per edge: 16 lanes x uint4 = 256B row; 16 gathers in flight.

__device__ inline void acc8(float* s, uint4 u) {
    float2 t;
    t = unpack_bf16(u.x); s[0] += t.x; s[1] += t.y;
    t = unpack_bf16(u.y); s[2] += t.x; s[3] += t.y;
    t = unpack_bf16(u.z); s[4] += t.x; s[5] += t.y;
    t = unpack_bf16(u.w); s[6] += t.x; s[7] += t.y;
}

__global__ __launch_bounds__(256) void agg1_kernel(
    const unsigned* __restrict__ G, const int* __restrict__ row_ptr,
    const int* __restrict__ csr_src, const float* __restrict__ dis,
    const float* __restrict__ b1, unsigned* __restrict__ H, int n) {
    int wid = (blockIdx.x * blockDim.x + threadIdx.x) >> 6;
    int lane = threadIdx.x & 63;
    if (wid >= n) return;
    int q = lane >> 4, hl = lane & 15;
    const char* Gb = (const char*)G;              // row = 256B
    unsigned lofs = (unsigned)(hl << 4);
    float s0[8] = {0,0,0,0,0,0,0,0}, s1[8] = {0,0,0,0,0,0,0,0};
    float s2[8] = {0,0,0,0,0,0,0,0}, s3[8] = {0,0,0,0,0,0,0,0};
    int beg = row_ptr[wid], end = row_ptr[wid + 1];
    for (int base = beg; base < end; base += 64) {
        int m = end - base; if (m > 64) m = 64;
        int idx = csr_src[base + (lane < m ? lane : m - 1)];
        int j = 0;
        for (; j + 16 <= m; j += 16) {
            unsigned o0 = ((unsigned)__shfl(idx, j +      q) << 8) + lofs;
            unsigned o1 = ((unsigned)__shfl(idx, j +  4 + q) << 8) + lofs;
            unsigned o2 = ((unsigned)__shfl(idx, j +  8 + q) << 8) + lofs;
            unsigned o3 = ((unsigned)__shfl(idx, j + 12 + q) << 8) + lofs;
            uint4 u0 = *(const uint4*)(Gb + o0);
            uint4 u1 = *(const uint4*)(Gb + o1);
            uint4 u2 = *(const uint4*)(Gb + o2);
            uint4 u3 = *(const uint4*)(Gb + o3);
            acc8(s0, u0); acc8(s1, u1); acc8(s2, u2); acc8(s3, u3);
        }
        for (; j + 4 <= m; j += 4) {
            unsigned o0 = ((unsigned)__shfl(idx, j + q) << 8) + lofs;
            uint4 u0 = *(const uint4*)(Gb + o0);
            acc8(s0, u0);
        }
        int rem = m - j;                          // 0..3
        if (rem) {
            int ii = __shfl(idx, j + (q < rem ? q : 0));
            if (q < rem) {
                uint4 u = *(const uint4*)(Gb + (((unsigned)ii << 8) + lofs));
                acc8(s0, u);
            }
        }
    }
    #pragma unroll
    for (int c = 0; c < 8; ++c) s0[c] += s1[c] + s2[c] + s3[c];
    #pragma unroll
    for (int c = 0; c < 8; ++c) {
        s0[c] += __shfl_xor(s0[c], 16);
        s0[c] += __shfl_xor(s0[c], 32);
    }
    uint4 su = *(const uint4*)(Gb + (((unsigned)wid << 8) + lofs));   // self
    acc8(s0, su);
    float d = dis[wid];
    float bb[8];
    *(float4*)&bb[0] = ((const float4*)b1)[hl * 2];
    *(float4*)&bb[4] = ((const float4*)b1)[hl * 2 + 1];
    float o[8];
    #pragma unroll
    for (int c = 0; c < 8; ++c) o[c] = fmaxf(fmaf(s0[c], d, bb[c]), 0.f);
    if (q == 0) {
        uint4 ou;
        ou.x = pack_bf16(o[0], o[1]);
        ou.y = pack_bf16(o[2], o[3]);
        ou.z = pack_bf16(o[4], o[5]);
        ou.w = pack_bf16(o[6], o[7]);
        *(uint4*)((char*)H + (((unsigned)wid << 8) + lofs)) = ou;
    }
}

// ---------------- Aggregation 2: out = dis .* (self+gather) + b2 -------------

__device__ inline void acc4(float* s, uint2 u) {
    float2 t;
    t = unpack_bf16(u.x); s[0] += t.x; s[1] += t.y;
    t = unpack_bf16(u.y); s[2] += t.x; s[3] += t.y;
}

__global__ __launch_bounds__(256) void agg2_kernel(
    const unsigned short* __restrict__ G, const int* __restrict__ row_ptr,
    const int* __restrict__ csr_src, const float* __restrict__ dis,
    const float* __restrict__ b2, float* __restrict__ out, int n) {
    int wid = (blockIdx.x * blockDim.x + threadIdx.x) >> 6;
    int lane = threadIdx.x & 63;
    if (wid >= n) return;
    int q = lane >> 4, hl = lane & 15;
    const char* Gb = (const char*)G;              // row = 128B
    unsigned lofs = (unsigned)(hl << 3);
    float s0[4] = {0,0,0,0}, s1[4] = {0,0,0,0}, s2[4] = {0,0,0,0}, s3[4] = {0,0,0,0};
    int beg = row_ptr[wid], end = row_ptr[wid + 1];
    for (int base = beg; base < end; base += 64) {
        int m = end - base; if (m > 64) m = 64;
        int idx = csr_src[base + (lane < m ? lane : m - 1)];
        int j = 0;
        for (; j + 16 <= m; j += 16) {
            unsigned o0 = ((unsigned)__shfl(idx, j +      q) << 7) + lofs;
            unsigned o1 = ((unsigned)__shfl(idx, j +  4 + q) << 7) + lofs;
            unsigned o2 = ((unsigned)__shfl(idx, j +  8 + q) << 7) + lofs;
            unsigned o3 = ((unsigned)__shfl(idx, j + 12 + q) << 7) + lofs;
            uint2 u0 = *(const uint2*)(Gb + o0);
            uint2 u1 = *(const uint2*)(Gb + o1);
            uint2 u2 = *(const uint2*)(Gb + o2);
            uint2 u3 = *(const uint2*)(Gb + o3);
            acc4(s0, u0); acc4(s1, u1); acc4(s2, u2); acc4(s3, u3);
        }
        for (; j + 4 <= m; j += 4) {
            unsigned o0 = ((unsigned)__shfl(idx, j + q) << 7) + lofs;
            uint2 u0 = *(const uint2*)(Gb + o0);
            acc4(s0, u0);
        }
        int rem = m - j;
        if (rem) {
            int ii = __shfl(idx, j + (q < rem ? q : 0));
            if (q < rem) {
                uint2 u = *(const uint2*)(Gb + (((unsigned)ii << 7) + lofs));
                acc4(s0, u);
            }
        }
    }
    #pragma unroll
    for (int c = 0; c < 4; ++c) s0[c] += s1[c] + s2[c] + s3[c];
    #pragma unroll
    for (int c = 0; c < 4; ++c) {
        s0[c] += __shfl_xor(s0[c], 16);
        s0[c] += __shfl_xor(s0[c], 32);
    }
    uint2 su = *(const uint2*)(Gb + (((unsigned)wid << 7) + lofs));   // self
    acc4(s0, su);
    float d = dis[wid];
    float4 bb = ((const float4*)b2)[hl];
    if (q == 0) {
        float4 o;
        o.x = fmaf(s0[0], d, bb.x);
        o.y = fmaf(s0[1], d, bb.y);
        o.z = fmaf(s0[2], d, bb.z);
        o.w = fmaf(s0[3], d, bb.w);
        ((float4*)out)[(size_t)wid * 16 + hl] = o;
    }
}

// ---------------- launch ----------------

extern "C" void kernel_launch(void* const* d_in, const int* in_sizes, int n_in,
                              void* d_out, int out_size, void* d_ws, size_t ws_size,
                              hipStream_t stream) {
    const float* x  = (const float*)d_in[0];
    const int*   ei = (const int*)d_in[1];
    const float* W1 = (const float*)d_in[2];
    const float* b1 = (const float*)d_in[3];
    const float* W2 = (const float*)d_in[4];
    const float* b2 = (const float*)d_in[5];
    float* out = (float*)d_out;

    int n = in_sizes[0] / IN_CH;       // 100000
    int E = in_sizes[1] / 2;           // 1600000
    const int* srcv = ei;
    const int* dstv = ei + E;

    int NB    = (E + EPB - 1) / EPB;   // 391 edge-blocks
    int NBUCK = (n + 255) >> 8;        // 391 buckets (256 nodes each)
    int L     = NBUCK * NB;

    char* w = (char*)d_ws;
    unsigned short* g1 = (unsigned short*)w;  w += (size_t)n * HID * 2;   // 25.6 MB
    unsigned short* h1 = (unsigned short*)w;  w += (size_t)n * HID * 2;   // 25.6 MB
    unsigned short* g2 = g1;                                              // overlay
    unsigned short* wt1 = (unsigned short*)w; w += (size_t)IN_CH * HID * 2;
    unsigned short* wt2 = (unsigned short*)w; w += (size_t)HID * OUT_CH * 2;
    unsigned short* lrank = (unsigned short*)w; w += (size_t)E * 2;       // 3.2 MB
    int*      blockhist = (int*)w; w += (size_t)L * 4;
    int*      rowsum    = (int*)w; w += (size_t)(NBUCK + 1) * 4;
    int*      flatscan  = (int*)w; w += (size_t)(L + 1) * 4;
    unsigned* sorted    = (unsigned*)w; w += (size_t)E * 4;               // 6.4 MB
    int*      csr       = (int*)w; w += (size_t)E * 4;                    // 6.4 MB
    int*      row_ptr   = (int*)w; w += (size_t)(n + 1) * 4;
    float*    dis       = (float*)w; w += (size_t)n * 4;

    int Gsz = NB > NBUCK ? NB : NBUCK;

    void* args[] = {
        (void*)&srcv, (void*)&dstv, (void*)&lrank, (void*)&blockhist,
        (void*)&rowsum, (void*)&flatscan, (void*)&sorted, (void*)&csr,
        (void*)&row_ptr, (void*)&dis,
        (void*)&W1, (void*)&wt1, (void*)&W2, (void*)&wt2,
        (void*)&E, (void*)&n, (void*)&NB, (void*)&NBUCK, (void*)&L
    };
    hipLaunchCooperativeKernel((const void*)csr_coop, dim3(Gsz), dim3(256),
                               args, 0, stream);

    gemm1_mfma<<<(n + 255) / 256, 512, 0, stream>>>(x, wt1, dis, g1, n);
    agg1_kernel<<<(n + 3) / 4, 256, 0, stream>>>((const unsigned*)g1, row_ptr, csr, dis, b1, (unsigned*)h1, n);
    gemm2_mfma<<<(n + 255) / 256, 512, 0, stream>>>(h1, wt2, dis, g2, n);
    agg2_kernel<<<(n + 3) / 4, 256, 0, stream>>>(g2, row_ptr, csr, dis, b2, out, n);
}

// Round 11
// 217.832 us; speedup vs baseline: 1.9497x; 1.9497x over previous
//
#include <hip/hip_runtime.h>

// ---------------------------------------------------------------------------
// GCN 2-layer forward on MI355X.
//  out = Ahat( relu( Ahat (X W1) + b1 ) W2 ) + b2,  Ahat = D^-1/2 (A+I) D^-1/2
// Factored: g = dis .* (X W);  s[i] = g[i] + sum_{e: dst=i} g[src[e]];
//           layer_out[i] = dis[i]*s[i] + b
// R11: REVERT cooperative fusion (grid.sync at 391 blocks = 256us, vs ~45us
//      for the 6-kernel chain). gemm1 retiled BM=128 -> 782 blocks, 4/CU,
//      32 waves/CU of TLP for the X stream; reg-prefetch pipeline kept.
// ---------------------------------------------------------------------------

constexpr int IN_CH  = 256;
constexpr int HID    = 128;
constexpr int OUT_CH = 64;
constexpr int EPB = 4096;         // edges per block in hist/scatter

typedef __attribute__((ext_vector_type(8))) short short8;
typedef __attribute__((ext_vector_type(4))) float f32x4;

union F8 {                       // one MFMA A/B fragment: 8 bf16
    short8 v;
    unsigned short u[8];
    uint4  q;
};

// ---- bf16 helpers (RNE) ----
__device__ inline unsigned short f2b(float f) {
    unsigned u = __float_as_uint(f);
    u += 0x7fffu + ((u >> 16) & 1u);
    return (unsigned short)(u >> 16);
}
__device__ inline unsigned pack_bf16(float a, float b) {
    unsigned ua = __float_as_uint(a); ua += 0x7fffu + ((ua >> 16) & 1u);
    unsigned ub = __float_as_uint(b); ub += 0x7fffu + ((ub >> 16) & 1u);
    return (ua >> 16) | (ub & 0xffff0000u);
}
__device__ inline float2 unpack_bf16(unsigned v) {
    return make_float2(__uint_as_float(v << 16), __uint_as_float(v & 0xffff0000u));
}

// ---------------- CSR build (bucket radix, LDS atomics only) ----------------

__global__ __launch_bounds__(256) void bucket_hist(
    const int* __restrict__ dst, unsigned short* __restrict__ lrank,
    int* __restrict__ blockhist, int E, int NB, int NBUCK) {
    __shared__ int lbin[512];
    for (int l = threadIdx.x; l < 512; l += 256) lbin[l] = 0;
    __syncthreads();
    int base = blockIdx.x * EPB;
    #pragma unroll 4
    for (int j = 0; j < EPB / 256; ++j) {
        int e = base + j * 256 + threadIdx.x;
        if (e < E) {
            int b = ((unsigned)dst[e]) >> 8;
            lrank[e] = (unsigned short)atomicAdd(&lbin[b], 1);
        }
    }
    __syncthreads();
    for (int l = threadIdx.x; l < NBUCK; l += 256)
        blockhist[l * NB + blockIdx.x] = lbin[l];   // bucket-major
}

__global__ void scan_partial_kernel(const int* __restrict__ in, int* __restrict__ partial, int len) {
    __shared__ int sh[256];
    int i = blockIdx.x * 256 + threadIdx.x;
    int v = (i < len) ? in[i] : 0;
    sh[threadIdx.x] = v;
    __syncthreads();
    for (int ofs = 128; ofs > 0; ofs >>= 1) {
        if (threadIdx.x < ofs) sh[threadIdx.x] += sh[threadIdx.x + ofs];
        __syncthreads();
    }
    if (threadIdx.x == 0) partial[blockIdx.x] = sh[0];
}

__global__ __launch_bounds__(1024) void scan_top_kernel(
    int* __restrict__ partial, int nb, int* __restrict__ out, int L) {
    __shared__ int sh[1024];
    int t = threadIdx.x;
    int v = (t < nb) ? partial[t] : 0;
    sh[t] = v;
    __syncthreads();
    for (int ofs = 1; ofs < 1024; ofs <<= 1) {
        int tv = (t >= ofs) ? sh[t - ofs] : 0;
        __syncthreads();
        sh[t] += tv;
        __syncthreads();
    }
    if (t < nb) partial[t] = sh[t] - v;          // exclusive
    if (t == 1023) out[L] = sh[1023];            // grand total (== E)
}

__global__ void scan_final_kernel(const int* __restrict__ in, const int* __restrict__ partial,
                                  int* __restrict__ out, int len) {
    __shared__ int sh[256];
    int i = blockIdx.x * 256 + threadIdx.x;
    int v = (i < len) ? in[i] : 0;
    sh[threadIdx.x] = v;
    __syncthreads();
    for (int ofs = 1; ofs < 256; ofs <<= 1) {
        int t = 0;
        if (threadIdx.x >= ofs) t = sh[threadIdx.x - ofs];
        __syncthreads();
        if (threadIdx.x >= ofs) sh[threadIdx.x] += t;
        __syncthreads();
    }
    if (i < len) out[i] = partial[blockIdx.x] + sh[threadIdx.x] - v;   // exclusive
}

__global__ __launch_bounds__(256) void bucket_scatter(
    const int* __restrict__ src, const int* __restrict__ dst,
    const unsigned short* __restrict__ lrank, const int* __restrict__ flatscan,
    unsigned* __restrict__ sorted, int E, int NB) {
    int base = blockIdx.x * EPB;
    #pragma unroll 4
    for (int j = 0; j < EPB / 256; ++j) {
        int e = base + j * 256 + threadIdx.x;
        if (e < E) {
            int d = dst[e];
            int b = ((unsigned)d) >> 8;
            int slot = flatscan[b * NB + blockIdx.x] + (int)lrank[e];
            sorted[slot] = (((unsigned)(d & 255)) << 24) | (unsigned)src[e];
        }
    }
}

__global__ __launch_bounds__(256) void bucket_finalize(
    const unsigned* __restrict__ sorted, const int* __restrict__ flatscan,
    int* __restrict__ csr_src, int* __restrict__ row_ptr, float* __restrict__ dis,
    int NB, int n) {
    __shared__ int cnt[256];
    __shared__ int sh[256];
    __shared__ int cur[256];
    int b = blockIdx.x;
    int t = threadIdx.x;
    int ebeg = flatscan[b * NB];
    int eend = flatscan[(b + 1) * NB];
    cnt[t] = 0;
    __syncthreads();
    for (int e = ebeg + t; e < eend; e += 256)
        atomicAdd(&cnt[sorted[e] >> 24], 1);
    __syncthreads();
    int v = cnt[t];
    sh[t] = v;
    __syncthreads();
    for (int ofs = 1; ofs < 256; ofs <<= 1) {
        int tv = (t >= ofs) ? sh[t - ofs] : 0;
        __syncthreads();
        sh[t] += tv;
        __syncthreads();
    }
    int excl = sh[t] - v;
    int node = b * 256 + t;
    if (node <= n) row_ptr[node] = ebeg + excl;
    if (node < n)  dis[node] = rsqrtf(1.0f + (float)v);
    cur[t] = excl;
    __syncthreads();
    for (int e = ebeg + t; e < eend; e += 256) {
        unsigned s = sorted[e];
        int pos = atomicAdd(&cur[s >> 24], 1);
        csr_src[ebeg + pos] = (int)(s & 0xFFFFFFu);
    }
}

// ---------------- W transpose + bf16: Wt[c][k] = bf16(W[k][c]) ---------------

__global__ void wt_kernel(const float* __restrict__ W, unsigned short* __restrict__ Wt,
                          int K, int N) {
    int idx = blockIdx.x * 256 + threadIdx.x;    // idx = c*K + k
    if (idx >= K * N) return;
    int c = idx / K, k = idx - c * K;
    Wt[idx] = f2b(W[(size_t)k * N + c]);
}

// ---------------- GEMM 1 (MFMA + LDS + reg prefetch, BM=128) -----------------
// Tile 128x128, 8 waves (2M x 4N), wave tile 64x32, BK=32, 8 K-steps.
// 782 blocks -> ~4/CU (20KB LDS, 512 thr) = 32 waves/CU of TLP.

__global__ __launch_bounds__(512) void gemm1_mfma(
    const float* __restrict__ X, const unsigned short* __restrict__ Wt,
    const float* __restrict__ dis, unsigned short* __restrict__ G, int n) {
    constexpr int K = 256, LP = 20, NS = 8;
    __shared__ unsigned xs[2][128 * LP];          // 2 x 10KB

    int tid  = threadIdx.x;
    int lane = tid & 63;
    int w    = tid >> 6;
    int wm = w >> 2, wn = w & 3;
    int rowbase = blockIdx.x * 128 + wm * 64;
    int colbase = wn * 32;
    int la = lane & 15, lb = lane >> 4;

    // staging: 128 rows x 32 floats per slab; thread -> (row=tid>>2, 8 floats)
    int srow = tid >> 2, sq = tid & 3;
    int grow = blockIdx.x * 128 + srow;
    if (grow >= n) grow = n - 1;
    const float* xrow = X + (size_t)grow * K + sq * 8;
    int sofs = srow * LP + sq * 4;                // uint offset in xs

    float4 pf0, pf1;
    #define G1_LOAD(ks) { const float* p_ = xrow + (ks) * 32;                 \
        pf0 = *(const float4*)(p_); pf1 = *(const float4*)(p_ + 4); }
    #define G1_WRITE(buf) { uint4 o_;                                         \
        o_.x = pack_bf16(pf0.x, pf0.y); o_.y = pack_bf16(pf0.z, pf0.w);       \
        o_.z = pack_bf16(pf1.x, pf1.y); o_.w = pack_bf16(pf1.z, pf1.w);       \
        *(uint4*)&xs[buf][sofs] = o_; }

    f32x4 acc[4][2];
    #pragma unroll
    for (int m = 0; m < 4; ++m)
        #pragma unroll
        for (int nn = 0; nn < 2; ++nn) acc[m][nn] = (f32x4){0.f, 0.f, 0.f, 0.f};

    G1_LOAD(0);
    G1_WRITE(0);
    G1_LOAD(1);
    __syncthreads();

    #pragma unroll
    for (int ks = 0; ks < NS; ++ks) {
        int cur = ks & 1;
        if (ks + 1 < NS) G1_WRITE(cur ^ 1);       // regs hold slab ks+1
        if (ks + 2 < NS) G1_LOAD(ks + 2);         // issue early, consume next step
        F8 a[4], b[2];
        #pragma unroll
        for (int m = 0; m < 4; ++m)
            a[m].q = *(const uint4*)&xs[cur][(wm * 64 + m * 16 + la) * LP + lb * 4];
        #pragma unroll
        for (int nn = 0; nn < 2; ++nn) {
            int col = colbase + nn * 16 + la;
            b[nn].q = *(const uint4*)(Wt + (size_t)col * K + ks * 32 + lb * 8);
        }
        #pragma unroll
        for (int m = 0; m < 4; ++m)
            #pragma unroll
            for (int nn = 0; nn < 2; ++nn)
                acc[m][nn] = __builtin_amdgcn_mfma_f32_16x16x32_bf16(
                    a[m].v, b[nn].v, acc[m][nn], 0, 0, 0);
        __syncthreads();
    }
    #undef G1_LOAD
    #undef G1_WRITE

    #pragma unroll
    for (int m = 0; m < 4; ++m) {
        int r0 = rowbase + m * 16 + lb * 4;
        float dv[4];
        #pragma unroll
        for (int r = 0; r < 4; ++r) dv[r] = (r0 + r < n) ? dis[r0 + r] : 0.f;
        #pragma unroll
        for (int nn = 0; nn < 2; ++nn) {
            int col = colbase + nn * 16 + la;
            #pragma unroll
            for (int r = 0; r < 4; ++r) {
                int row = r0 + r;
                if (row < n)
                    G[(size_t)row * HID + col] = f2b(acc[m][nn][r] * dv[r]);
            }
        }
    }
}

// ---------------- GEMM 2 (MFMA + LDS + reg prefetch) -------------------------
// Tile 256x64, 8 waves (4M x 2N), wave tile 64x32, BK=32, 4 K-steps.

__global__ __launch_bounds__(512) void gemm2_mfma(
    const unsigned short* __restrict__ H, const unsigned short* __restrict__ Wt,
    const float* __restrict__ dis, unsigned short* __restrict__ G, int n) {
    constexpr int K = 128, LP = 20, NS = 4;
    __shared__ unsigned xs[2][256 * LP];

    int tid  = threadIdx.x;
    int lane = tid & 63;
    int w    = tid >> 6;
    int wm = w >> 1, wn = w & 1;
    int rowbase = blockIdx.x * 256 + wm * 64;
    int colbase = wn * 32;
    int la = lane & 15, lb = lane >> 4;

    const unsigned* Hu = (const unsigned*)H;      // 64 uints per row

    int sr0 = tid >> 2, sq0 = tid & 3;
    int sr1 = (tid + 512) >> 2, sq1 = tid & 3;
    int g0 = blockIdx.x * 256 + sr0; g0 = g0 < n ? g0 : n - 1;
    int g1 = blockIdx.x * 256 + sr1; g1 = g1 < n ? g1 : n - 1;

    uint4 pf0, pf1;
    #define G2_LOAD(ks) {                                                     \
        pf0 = *(const uint4*)&Hu[(size_t)g0 * 64 + (ks) * 16 + sq0 * 4];      \
        pf1 = *(const uint4*)&Hu[(size_t)g1 * 64 + (ks) * 16 + sq1 * 4]; }
    #define G2_WRITE(buf) {                                                   \
        *(uint4*)&xs[buf][sr0 * LP + sq0 * 4] = pf0;                          \
        *(uint4*)&xs[buf][sr1 * LP + sq1 * 4] = pf1; }

    f32x4 acc[4][2];
    #pragma unroll
    for (int m = 0; m < 4; ++m)
        #pragma unroll
        for (int nn = 0; nn < 2; ++nn) acc[m][nn] = (f32x4){0.f, 0.f, 0.f, 0.f};

    G2_LOAD(0);
    G2_WRITE(0);
    G2_LOAD(1);
    __syncthreads();

    #pragma unroll
    for (int ks = 0; ks < NS; ++ks) {
        int cur = ks & 1;
        if (ks + 1 < NS) G2_WRITE(cur ^ 1);
        if (ks + 2 < NS) G2_LOAD(ks + 2);
        F8 a[4], b[2];
        #pragma unroll
        for (int m = 0; m < 4; ++m)
            a[m].q = *(const uint4*)&xs[cur][(wm * 64 + m * 16 + la) * LP + lb * 4];
        #pragma unroll
        for (int nn = 0; nn < 2; ++nn) {
            int col = colbase + nn * 16 + la;
            b[nn].q = *(const uint4*)(Wt + (size_t)col * K + ks * 32 + lb * 8);
        }
        #pragma unroll
        for (int m = 0; m < 4; ++m)
            #pragma unroll
            for (int nn = 0; nn < 2; ++nn)
                acc[m][nn] = __builtin_amdgcn_mfma_f32_16x16x32_bf16(
                    a[m].v, b[nn].v, acc[m][nn], 0, 0, 0);
        __syncthreads();
    }
    #undef G2_LOAD
    #undef G2_WRITE

    #pragma unroll
    for (int m = 0; m < 4; ++m) {
        int r0 = rowbase + m * 16 + lb * 4;
        float dv[4];
        #pragma unroll
        for (int r = 0; r < 4; ++r) dv[r] = (r0 + r < n) ? dis[r0 + r] : 0.f;
        #pragma unroll
        for (int nn = 0; nn < 2; ++nn) {
            int col = colbase + nn * 16 + la;
            #pragma unroll
            for (int r = 0; r < 4; ++r) {
                int row = r0 + r;
                if (row < n)
                    G[(size_t)row * OUT_CH + col] = f2b(acc[m][nn][r] * dv[r]);
            }
        }
    }
}

// ---------------- Aggregation 1: h1 = bf16(relu(dis .* (self+gather) + b1)) --
// Quarter-wave per edge: 16 lanes x uint4 = 256B row; 16 gathers in flight.

__device__ inline void acc8(float* s, uint4 u) {
    float2 t;
    t = unpack_bf16(u.x); s[0] += t.x; s[1] += t.y;
    t = unpack_bf16(u.y); s[2] += t.x; s[3] += t.y;
    t = unpack_bf16(u.z); s[4] += t.x; s[5] += t.y;
    t = unpack_bf16(u.w); s[6] += t.x; s[7] += t.y;
}

__global__ __launch_bounds__(256) void agg1_kernel(
    const unsigned* __restrict__ G, const int* __restrict__ row_ptr,
    const int* __restrict__ csr_src, const float* __restrict__ dis,
    const float* __restrict__ b1, unsigned* __restrict__ H, int n) {
    int wid = (blockIdx.x * blockDim.x + threadIdx.x) >> 6;
    int lane = threadIdx.x & 63;
    if (wid >= n) return;
    int q = lane >> 4, hl = lane & 15;
    const char* Gb = (const char*)G;              // row = 256B
    unsigned lofs = (unsigned)(hl << 4);
    float s0[8] = {0,0,0,0,0,0,0,0}, s1[8] = {0,0,0,0,0,0,0,0};
    float s2[8] = {0,0,0,0,0,0,0,0}, s3[8] = {0,0,0,0,0,0,0,0};
    int beg = row_ptr[wid], end = row_ptr[wid + 1];
    for (int base = beg; base < end; base += 64) {
        int m = end - base; if (m > 64) m = 64;
        int idx = csr_src[base + (lane < m ? lane : m - 1)];
        int j = 0;
        for (; j + 16 <= m; j += 16) {
            unsigned o0 = ((unsigned)__shfl(idx, j +      q) << 8) + lofs;
            unsigned o1 = ((unsigned)__shfl(idx, j +  4 + q) << 8) + lofs;
            unsigned o2 = ((unsigned)__shfl(idx, j +  8 + q) << 8) + lofs;
            unsigned o3 = ((unsigned)__shfl(idx, j + 12 + q) << 8) + lofs;
            uint4 u0 = *(const uint4*)(Gb + o0);
            uint4 u1 = *(const uint4*)(Gb + o1);
            uint4 u2 = *(const uint4*)(Gb + o2);
            uint4 u3 = *(const uint4*)(Gb + o3);
            acc8(s0, u0); acc8(s1, u1); acc8(s2, u2); acc8(s3, u3);
        }
        for (; j + 4 <= m; j += 4) {
            unsigned o0 = ((unsigned)__shfl(idx, j + q) << 8) + lofs;
            uint4 u0 = *(const uint4*)(Gb + o0);
            acc8(s0, u0);
        }
        int rem = m - j;                          // 0..3
        if (rem) {
            int ii = __shfl(idx, j + (q < rem ? q : 0));
            if (q < rem) {
                uint4 u = *(const uint4*)(Gb + (((unsigned)ii << 8) + lofs));
                acc8(s0, u);
            }
        }
    }
    #pragma unroll
    for (int c = 0; c < 8; ++c) s0[c] += s1[c] + s2[c] + s3[c];
    #pragma unroll
    for (int c = 0; c < 8; ++c) {
        s0[c] += __shfl_xor(s0[c], 16);
        s0[c] += __shfl_xor(s0[c], 32);
    }
    uint4 su = *(const uint4*)(Gb + (((unsigned)wid << 8) + lofs));   // self
    acc8(s0, su);
    float d = dis[wid];
    float bb[8];
    *(float4*)&bb[0] = ((const float4*)b1)[hl * 2];
    *(float4*)&bb[4] = ((const float4*)b1)[hl * 2 + 1];
    float o[8];
    #pragma unroll
    for (int c = 0; c < 8; ++c) o[c] = fmaxf(fmaf(s0[c], d, bb[c]), 0.f);
    if (q == 0) {
        uint4 ou;
        ou.x = pack_bf16(o[0], o[1]);
        ou.y = pack_bf16(o[2], o[3]);
        ou.z = pack_bf16(o[4], o[5]);
        ou.w = pack_bf16(o[6], o[7]);
        *(uint4*)((char*)H + (((unsigned)wid << 8) + lofs)) = ou;
    }
}

// ---------------- Aggregation 2: out = dis .* (self+gather) + b2 -------------

__device__ inline void acc4(float* s, uint2 u) {
    float2 t;
    t = unpack_bf16(u.x); s[0] += t.x; s[1] += t.y;
    t = unpack_bf16(u.y); s[2] += t.x; s[3] += t.y;
}

__global__ __launch_bounds__(256) void agg2_kernel(
    const unsigned short* __restrict__ G, const int* __restrict__ row_ptr,
    const int* __restrict__ csr_src, const float* __restrict__ dis,
    const float* __restrict__ b2, float* __restrict__ out, int n) {
    int wid = (blockIdx.x * blockDim.x + threadIdx.x) >> 6;
    int lane = threadIdx.x & 63;
    if (wid >= n) return;
    int q = lane >> 4, hl = lane & 15;
    const char* Gb = (const char*)G;              // row = 128B
    unsigned lofs = (unsigned)(hl << 3);
    float s0[4] = {0,0,0,0}, s1[4] = {0,0,0,0}, s2[4] = {0,0,0,0}, s3[4] = {0,0,0,0};
    int beg = row_ptr[wid], end = row_ptr[wid + 1];
    for (int base = beg; base < end; base += 64) {
        int m = end - base; if (m > 64) m = 64;
        int idx = csr_src[base + (lane < m ? lane : m - 1)];
        int j = 0;
        for (; j + 16 <= m; j += 16) {
            unsigned o0 = ((unsigned)__shfl(idx, j +      q) << 7) + lofs;
            unsigned o1 = ((unsigned)__shfl(idx, j +  4 + q) << 7) + lofs;
            unsigned o2 = ((unsigned)__shfl(idx, j +  8 + q) << 7) + lofs;
            unsigned o3 = ((unsigned)__shfl(idx, j + 12 + q) << 7) + lofs;
            uint2 u0 = *(const uint2*)(Gb + o0);
            uint2 u1 = *(const uint2*)(Gb + o1);
            uint2 u2 = *(const uint2*)(Gb + o2);
            uint2 u3 = *(const uint2*)(Gb + o3);
            acc4(s0, u0); acc4(s1, u1); acc4(s2, u2); acc4(s3, u3);
        }
        for (; j + 4 <= m; j += 4) {
            unsigned o0 = ((unsigned)__shfl(idx, j + q) << 7) + lofs;
            uint2 u0 = *(const uint2*)(Gb + o0);
            acc4(s0, u0);
        }
        int rem = m - j;
        if (rem) {
            int ii = __shfl(idx, j + (q < rem ? q : 0));
            if (q < rem) {
                uint2 u = *(const uint2*)(Gb + (((unsigned)ii << 7) + lofs));
                acc4(s0, u);
            }
        }
    }
    #pragma unroll
    for (int c = 0; c < 4; ++c) s0[c] += s1[c] + s2[c] + s3[c];
    #pragma unroll
    for (int c = 0; c < 4; ++c) {
        s0[c] += __shfl_xor(s0[c], 16);
        s0[c] += __shfl_xor(s0[c], 32);
    }
    uint2 su = *(const uint2*)(Gb + (((unsigned)wid << 7) + lofs));   // self
    acc4(s0, su);
    float d = dis[wid];
    float4 bb = ((const float4*)b2)[hl];
    if (q == 0) {
        float4 o;
        o.x = fmaf(s0[0], d, bb.x);
        o.y = fmaf(s0[1], d, bb.y);
        o.z = fmaf(s0[2], d, bb.z);
        o.w = fmaf(s0[3], d, bb.w);
        ((float4*)out)[(size_t)wid * 16 + hl] = o;
    }
}

// ---------------- launch ----------------

extern "C" void kernel_launch(void* const* d_in, const int* in_sizes, int n_in,
                              void* d_out, int out_size, void* d_ws, size_t ws_size,
                              hipStream_t stream) {
    const float* x  = (const float*)d_in[0];
    const int*   ei = (const int*)d_in[1];
    const float* W1 = (const float*)d_in[2];
    const float* b1 = (const float*)d_in[3];
    const float* W2 = (const float*)d_in[4];
    const float* b2 = (const float*)d_in[5];
    float* out = (float*)d_out;

    int n = in_sizes[0] / IN_CH;       // 100000
    int E = in_sizes[1] / 2;           // 1600000
    const int* srcv = ei;
    const int* dstv = ei + E;

    int NB    = (E + EPB - 1) / EPB;   // 391 edge-blocks
    int NBUCK = (n + 255) >> 8;        // 391 buckets (256 nodes each)
    int L     = NBUCK * NB;

    char* w = (char*)d_ws;
    unsigned short* g1 = (unsigned short*)w;  w += (size_t)n * HID * 2;   // 25.6 MB
    unsigned short* h1 = (unsigned short*)w;  w += (size_t)n * HID * 2;   // 25.6 MB
    unsigned short* g2 = g1;                                              // overlay
    unsigned short* wt1 = (unsigned short*)w; w += (size_t)IN_CH * HID * 2;
    unsigned short* wt2 = (unsigned short*)w; w += (size_t)HID * OUT_CH * 2;
    unsigned short* lrank = (unsigned short*)w; w += (size_t)E * 2;       // 3.2 MB
    int*      blockhist = (int*)w; w += (size_t)L * 4;
    int*      flatscan  = (int*)w; w += (size_t)(L + 1) * 4;
    int*      partial   = (int*)w; w += (size_t)1024 * 4;
    unsigned* sorted    = (unsigned*)w; w += (size_t)E * 4;               // 6.4 MB
    int*      csr       = (int*)w; w += (size_t)E * 4;                    // 6.4 MB
    int*      row_ptr   = (int*)w; w += (size_t)(n + 1) * 4;
    float*    dis       = (float*)w; w += (size_t)n * 4;

    int nb2 = (L + 255) / 256;

    bucket_hist<<<NB, 256, 0, stream>>>(dstv, lrank, blockhist, E, NB, NBUCK);
    scan_partial_kernel<<<nb2, 256, 0, stream>>>(blockhist, partial, L);
    scan_top_kernel<<<1, 1024, 0, stream>>>(partial, nb2, flatscan, L);
    scan_final_kernel<<<nb2, 256, 0, stream>>>(blockhist, partial, flatscan, L);
    bucket_scatter<<<NB, 256, 0, stream>>>(srcv, dstv, lrank, flatscan, sorted, E, NB);
    bucket_finalize<<<NBUCK, 256, 0, stream>>>(sorted, flatscan, csr, row_ptr, dis, NB, n);

    wt_kernel<<<(IN_CH * HID + 255) / 256, 256, 0, stream>>>(W1, wt1, IN_CH, HID);
    wt_kernel<<<(HID * OUT_CH + 255) / 256, 256, 0, stream>>>(W2, wt2, HID, OUT_CH);

    gemm1_mfma<<<(n + 127) / 128, 512, 0, stream>>>(x, wt1, dis, g1, n);
    agg1_kernel<<<(n + 3) / 4, 256, 0, stream>>>((const unsigned*)g1, row_ptr, csr, dis, b1, (unsigned*)h1, n);
    gemm2_mfma<<<(n + 255) / 256, 512, 0, stream>>>(h1, wt2, dis, g2, n);
    agg2_kernel<<<(n + 3) / 4, 256, 0, stream>>>(g2, row_ptr, csr, dis, b2, out, n);
}

// Round 12
// 208.306 us; speedup vs baseline: 2.0389x; 1.0457x over previous
//
#include <hip/hip_runtime.h>

// ---------------------------------------------------------------------------
// GCN 2-layer forward on MI355X.
//  out = Ahat( relu( Ahat (X W1) + b1 ) W2 ) + b2,  Ahat = D^-1/2 (A+I) D^-1/2
// Factored: g = dis .* (X W);  s[i] = g[i] + sum_{e: dst=i} g[src[e]];
//           layer_out[i] = dis[i]*s[i] + b
// R12: CSR chain 8->5 dispatches: lrank eliminated (scatter re-ranks via LDS
//      cursors), wt-convert fused into hist, 3-kernel scan merged into 2
//      (1024-chunks + redundant top-scan). agg/gemm at their traffic floors:
//      agg1 = 190MB fabric fill (8 XCD x 25.6MB) @ ~3.4TB/s — invariant
//      across 3 structural variants; fp8 ruled out by error budget.
// ---------------------------------------------------------------------------

constexpr int IN_CH  = 256;
constexpr int HID    = 128;
constexpr int OUT_CH = 64;
constexpr int EPB = 4096;         // edges per block in hist/scatter

typedef __attribute__((ext_vector_type(8))) short short8;
typedef __attribute__((ext_vector_type(4))) float f32x4;

union F8 {                       // one MFMA A/B fragment: 8 bf16
    short8 v;
    unsigned short u[8];
    uint4  q;
};

// ---- bf16 helpers (RNE) ----
__device__ inline unsigned short f2b(float f) {
    unsigned u = __float_as_uint(f);
    u += 0x7fffu + ((u >> 16) & 1u);
    return (unsigned short)(u >> 16);
}
__device__ inline unsigned pack_bf16(float a, float b) {
    unsigned ua = __float_as_uint(a); ua += 0x7fffu + ((ua >> 16) & 1u);
    unsigned ub = __float_as_uint(b); ub += 0x7fffu + ((ub >> 16) & 1u);
    return (ua >> 16) | (ub & 0xffff0000u);
}
__device__ inline float2 unpack_bf16(unsigned v) {
    return make_float2(__uint_as_float(v << 16), __uint_as_float(v & 0xffff0000u));
}

// ---------------- CSR build (bucket radix, LDS atomics only) ----------------
// bucket = dst >> 8 (256 nodes/bucket). No global atomics anywhere.

// P1: per-block 512-bin count histogram. Fused: W1/W2 -> bf16 W^T convert.
__global__ __launch_bounds__(256) void bucket_hist(
    const int* __restrict__ dst, int* __restrict__ blockhist,
    const float* __restrict__ W1, unsigned short* __restrict__ wt1,
    const float* __restrict__ W2, unsigned short* __restrict__ wt2,
    int E, int NB, int NBUCK) {
    __shared__ int lbin[512];
    for (int l = threadIdx.x; l < 512; l += 256) lbin[l] = 0;
    __syncthreads();
    // fused weight transpose+convert (41K elements over 100K threads)
    constexpr int NWT1 = IN_CH * HID;      // 32768
    constexpr int NWT2 = HID * OUT_CH;     // 8192
    for (int i = blockIdx.x * 256 + threadIdx.x; i < NWT1 + NWT2; i += gridDim.x * 256) {
        if (i < NWT1) {
            int c = i >> 8, k = i & 255;               // wt1[c*256+k] = W1[k][c]
            wt1[i] = f2b(W1[k * HID + c]);
        } else {
            int j = i - NWT1;
            int c = j >> 7, k = j & 127;               // wt2[c*128+k] = W2[k][c]
            wt2[j] = f2b(W2[k * OUT_CH + c]);
        }
    }
    int base = blockIdx.x * EPB;
    #pragma unroll 4
    for (int j = 0; j < EPB / 256; ++j) {
        int e = base + j * 256 + threadIdx.x;
        if (e < E) atomicAdd(&lbin[((unsigned)dst[e]) >> 8], 1);
    }
    __syncthreads();
    for (int l = threadIdx.x; l < NBUCK; l += 256)
        blockhist[l * NB + blockIdx.x] = lbin[l];   // bucket-major
}

// P2a: per-1024-chunk totals.
__global__ __launch_bounds__(1024) void scan_partial_kernel(
    const int* __restrict__ in, int* __restrict__ partial, int len) {
    __shared__ int sh[1024];
    int i = blockIdx.x * 1024 + threadIdx.x;
    sh[threadIdx.x] = (i < len) ? in[i] : 0;
    __syncthreads();
    for (int ofs = 512; ofs > 0; ofs >>= 1) {
        if (threadIdx.x < ofs) sh[threadIdx.x] += sh[threadIdx.x + ofs];
        __syncthreads();
    }
    if (threadIdx.x == 0) partial[blockIdx.x] = sh[0];
}

// P2b: exclusive scan -> out[0..len); each block redundantly scans the chunk
// partials in LDS (nchunks <= 1024), then scans its own 1024-element chunk.
__global__ __launch_bounds__(1024) void scan_topfinal_kernel(
    const int* __restrict__ in, const int* __restrict__ partial,
    int nchunks, int* __restrict__ out, int L) {
    __shared__ int top[1024];
    __shared__ int sh[1024];
    int t = threadIdx.x;
    top[t] = (t < nchunks) ? partial[t] : 0;
    int i = blockIdx.x * 1024 + t;
    int v = (i < L) ? in[i] : 0;
    sh[t] = v;
    __syncthreads();
    for (int ofs = 1; ofs < 1024; ofs <<= 1) {
        int a = (t >= ofs) ? top[t - ofs] : 0;
        int b = (t >= ofs) ? sh[t - ofs] : 0;
        __syncthreads();
        top[t] += a; sh[t] += b;
        __syncthreads();
    }
    int base = (blockIdx.x > 0) ? top[blockIdx.x - 1] : 0;   // exclusive chunk base
    if (i < L) out[i] = base + sh[t] - v;                    // exclusive
    if (blockIdx.x == 0 && t == 0) out[L] = top[nchunks - 1];  // grand total == E
}

// P3: scatter into bucket-sorted order; ranks re-derived via LDS cursors
// initialized from flatscan (any within-(block,bucket) permutation is valid).
__global__ __launch_bounds__(256) void bucket_scatter(
    const int* __restrict__ src, const int* __restrict__ dst,
    const int* __restrict__ flatscan, unsigned* __restrict__ sorted,
    int E, int NB, int NBUCK) {
    __shared__ int cur[512];
    for (int l = threadIdx.x; l < NBUCK; l += 256)
        cur[l] = flatscan[l * NB + blockIdx.x];
    __syncthreads();
    int base = blockIdx.x * EPB;
    #pragma unroll 4
    for (int j = 0; j < EPB / 256; ++j) {
        int e = base + j * 256 + threadIdx.x;
        if (e < E) {
            int d = dst[e];
            int bk = ((unsigned)d) >> 8;
            int slot = atomicAdd(&cur[bk], 1);
            sorted[slot] = (((unsigned)(d & 255)) << 24) | (unsigned)src[e];
        }
    }
}

// P4: one block per bucket (256 nodes): count, scan, row_ptr, dis, csr place.
__global__ __launch_bounds__(256) void bucket_finalize(
    const unsigned* __restrict__ sorted, const int* __restrict__ flatscan,
    int* __restrict__ csr_src, int* __restrict__ row_ptr, float* __restrict__ dis,
    int NB, int n) {
    __shared__ int cnt[256];
    __shared__ int sh[256];
    __shared__ int cur[256];
    int b = blockIdx.x;
    int t = threadIdx.x;
    int ebeg = flatscan[b * NB];
    int eend = flatscan[(b + 1) * NB];     // last bucket -> flatscan[L] = E
    cnt[t] = 0;
    __syncthreads();
    for (int e = ebeg + t; e < eend; e += 256)
        atomicAdd(&cnt[sorted[e] >> 24], 1);
    __syncthreads();
    int v = cnt[t];
    sh[t] = v;
    __syncthreads();
    for (int ofs = 1; ofs < 256; ofs <<= 1) {
        int tv = (t >= ofs) ? sh[t - ofs] : 0;
        __syncthreads();
        sh[t] += tv;
        __syncthreads();
    }
    int excl = sh[t] - v;
    int node = b * 256 + t;
    if (node <= n) row_ptr[node] = ebeg + excl;
    if (node < n)  dis[node] = rsqrtf(1.0f + (float)v);
    cur[t] = excl;
    __syncthreads();
    for (int e = ebeg + t; e < eend; e += 256) {
        unsigned s = sorted[e];
        int pos = atomicAdd(&cur[s >> 24], 1);
        csr_src[ebeg + pos] = (int)(s & 0xFFFFFFu);
    }
}

// ---------------- GEMM 1 (MFMA + LDS + reg prefetch, BM=128) -----------------

__global__ __launch_bounds__(512) void gemm1_mfma(
    const float* __restrict__ X, const unsigned short* __restrict__ Wt,
    const float* __restrict__ dis, unsigned short* __restrict__ G, int n) {
    constexpr int K = 256, LP = 20, NS = 8;
    __shared__ unsigned xs[2][128 * LP];          // 2 x 10KB

    int tid  = threadIdx.x;
    int lane = tid & 63;
    int w    = tid >> 6;
    int wm = w >> 2, wn = w & 3;
    int rowbase = blockIdx.x * 128 + wm * 64;
    int colbase = wn * 32;
    int la = lane & 15, lb = lane >> 4;

    int srow = tid >> 2, sq = tid & 3;
    int grow = blockIdx.x * 128 + srow;
    if (grow >= n) grow = n - 1;
    const float* xrow = X + (size_t)grow * K + sq * 8;
    int sofs = srow * LP + sq * 4;                // uint offset in xs

    float4 pf0, pf1;
    #define G1_LOAD(ks) { const float* p_ = xrow + (ks) * 32;                 \
        pf0 = *(const float4*)(p_); pf1 = *(const float4*)(p_ + 4); }
    #define G1_WRITE(buf) { uint4 o_;                                         \
        o_.x = pack_bf16(pf0.x, pf0.y); o_.y = pack_bf16(pf0.z, pf0.w);       \
        o_.z = pack_bf16(pf1.x, pf1.y); o_.w = pack_bf16(pf1.z, pf1.w);       \
        *(uint4*)&xs[buf][sofs] = o_; }

    f32x4 acc[4][2];
    #pragma unroll
    for (int m = 0; m < 4; ++m)
        #pragma unroll
        for (int nn = 0; nn < 2; ++nn) acc[m][nn] = (f32x4){0.f, 0.f, 0.f, 0.f};

    G1_LOAD(0);
    G1_WRITE(0);
    G1_LOAD(1);
    __syncthreads();

    #pragma unroll
    for (int ks = 0; ks < NS; ++ks) {
        int cur = ks & 1;
        if (ks + 1 < NS) G1_WRITE(cur ^ 1);       // regs hold slab ks+1
        if (ks + 2 < NS) G1_LOAD(ks + 2);         // issue early, consume next step
        F8 a[4], b[2];
        #pragma unroll
        for (int m = 0; m < 4; ++m)
            a[m].q = *(const uint4*)&xs[cur][(wm * 64 + m * 16 + la) * LP + lb * 4];
        #pragma unroll
        for (int nn = 0; nn < 2; ++nn) {
            int col = colbase + nn * 16 + la;
            b[nn].q = *(const uint4*)(Wt + (size_t)col * K + ks * 32 + lb * 8);
        }
        #pragma unroll
        for (int m = 0; m < 4; ++m)
            #pragma unroll
            for (int nn = 0; nn < 2; ++nn)
                acc[m][nn] = __builtin_amdgcn_mfma_f32_16x16x32_bf16(
                    a[m].v, b[nn].v, acc[m][nn], 0, 0, 0);
        __syncthreads();
    }
    #undef G1_LOAD
    #undef G1_WRITE

    #pragma unroll
    for (int m = 0; m < 4; ++m) {
        int r0 = rowbase + m * 16 + lb * 4;
        float dv[4];
        #pragma unroll
        for (int r = 0; r < 4; ++r) dv[r] = (r0 + r < n) ? dis[r0 + r] : 0.f;
        #pragma unroll
        for (int nn = 0; nn < 2; ++nn) {
            int col = colbase + nn * 16 + la;
            #pragma unroll
            for (int r = 0; r < 4; ++r) {
                int row = r0 + r;
                if (row < n)
                    G[(size_t)row * HID + col] = f2b(acc[m][nn][r] * dv[r]);
            }
        }
    }
}

// ---------------- GEMM 2 (MFMA + LDS + reg prefetch) -------------------------

__global__ __launch_bounds__(512) void gemm2_mfma(
    const unsigned short* __restrict__ H, const unsigned short* __restrict__ Wt,
    const float* __restrict__ dis, unsigned short* __restrict__ G, int n) {
    constexpr int K = 128, LP = 20, NS = 4;
    __shared__ unsigned xs[2][256 * LP];

    int tid  = threadIdx.x;
    int lane = tid & 63;
    int w    = tid >> 6;
    int wm = w >> 1, wn = w & 1;
    int rowbase = blockIdx.x * 256 + wm * 64;
    int colbase = wn * 32;
    int la = lane & 15, lb = lane >> 4;

    const unsigned* Hu = (const unsigned*)H;      // 64 uints per row

    int sr0 = tid >> 2, sq0 = tid & 3;
    int sr1 = (tid + 512) >> 2, sq1 = tid & 3;
    int g0 = blockIdx.x * 256 + sr0; g0 = g0 < n ? g0 : n - 1;
    int g1 = blockIdx.x * 256 + sr1; g1 = g1 < n ? g1 : n - 1;

    uint4 pf0, pf1;
    #define G2_LOAD(ks) {                                                     \
        pf0 = *(const uint4*)&Hu[(size_t)g0 * 64 + (ks) * 16 + sq0 * 4];      \
        pf1 = *(const uint4*)&Hu[(size_t)g1 * 64 + (ks) * 16 + sq1 * 4]; }
    #define G2_WRITE(buf) {                                                   \
        *(uint4*)&xs[buf][sr0 * LP + sq0 * 4] = pf0;                          \
        *(uint4*)&xs[buf][sr1 * LP + sq1 * 4] = pf1; }

    f32x4 acc[4][2];
    #pragma unroll
    for (int m = 0; m < 4; ++m)
        #pragma unroll
        for (int nn = 0; nn < 2; ++nn) acc[m][nn] = (f32x4){0.f, 0.f, 0.f, 0.f};

    G2_LOAD(0);
    G2_WRITE(0);
    G2_LOAD(1);
    __syncthreads();

    #pragma unroll
    for (int ks = 0; ks < NS; ++ks) {
        int cur = ks & 1;
        if (ks + 1 < NS) G2_WRITE(cur ^ 1);
        if (ks + 2 < NS) G2_LOAD(ks + 2);
        F8 a[4], b[2];
        #pragma unroll
        for (int m = 0; m < 4; ++m)
            a[m].q = *(const uint4*)&xs[cur][(wm * 64 + m * 16 + la) * LP + lb * 4];
        #pragma unroll
        for (int nn = 0; nn < 2; ++nn) {
            int col = colbase + nn * 16 + la;
            b[nn].q = *(const uint4*)(Wt + (size_t)col * K + ks * 32 + lb * 8);
        }
        #pragma unroll
        for (int m = 0; m < 4; ++m)
            #pragma unroll
            for (int nn = 0; nn < 2; ++nn)
                acc[m][nn] = __builtin_amdgcn_mfma_f32_16x16x32_bf16(
                    a[m].v, b[nn].v, acc[m][nn], 0, 0, 0);
        __syncthreads();
    }
    #undef G2_LOAD
    #undef G2_WRITE

    #pragma unroll
    for (int m = 0; m < 4; ++m) {
        int r0 = rowbase + m * 16 + lb * 4;
        float dv[4];
        #pragma unroll
        for (int r = 0; r < 4; ++r) dv[r] = (r0 + r < n) ? dis[r0 + r] : 0.f;
        #pragma unroll
        for (int nn = 0; nn < 2; ++nn) {
            int col = colbase + nn * 16 + la;
            #pragma unroll
            for (int r = 0; r < 4; ++r) {
                int row = r0 + r;
                if (row < n)
                    G[(size_t)row * OUT_CH + col] = f2b(acc[m][nn][r] * dv[r]);
            }
        }
    }
}

// ---------------- Aggregation 1: h1 = bf16(relu(dis .* (self+gather) + b1)) --
// Quarter-wave per edge: 16 lanes x uint4 = 256B row; 16 gathers in flight.

__device__ inline void acc8(float* s, uint4 u) {
    float2 t;
    t = unpack_bf16(u.x); s[0] += t.x; s[1] += t.y;
    t = unpack_bf16(u.y); s[2] += t.x; s[3] += t.y;
    t = unpack_bf16(u.z); s[4] += t.x; s[5] += t.y;
    t = unpack_bf16(u.w); s[6] += t.x; s[7] += t.y;
}

__global__ __launch_bounds__(256) void agg1_kernel(
    const unsigned* __restrict__ G, const int* __restrict__ row_ptr,
    const int* __restrict__ csr_src, const float* __restrict__ dis,
    const float* __restrict__ b1, unsigned* __restrict__ H, int n) {
    int wid = (blockIdx.x * blockDim.x + threadIdx.x) >> 6;
    int lane = threadIdx.x & 63;
    if (wid >= n) return;
    int q = lane >> 4, hl = lane & 15;
    const char* Gb = (const char*)G;              // row = 256B
    unsigned lofs = (unsigned)(hl << 4);
    float s0[8] = {0,0,0,0,0,0,0,0}, s1[8] = {0,0,0,0,0,0,0,0};
    float s2[8] = {0,0,0,0,0,0,0,0}, s3[8] = {0,0,0,0,0,0,0,0};
    int beg = row_ptr[wid], end = row_ptr[wid + 1];
    for (int base = beg; base < end; base += 64) {
        int m = end - base; if (m > 64) m = 64;
        int idx = csr_src[base + (lane < m ? lane : m - 1)];
        int j = 0;
        for (; j + 16 <= m; j += 16) {
            unsigned o0 = ((unsigned)__shfl(idx, j +      q) << 8) + lofs;
            unsigned o1 = ((unsigned)__shfl(idx, j +  4 + q) << 8) + lofs;
            unsigned o2 = ((unsigned)__shfl(idx, j +  8 + q) << 8) + lofs;
            unsigned o3 = ((unsigned)__shfl(idx, j + 12 + q) << 8) + lofs;
            uint4 u0 = *(const uint4*)(Gb + o0);
            uint4 u1 = *(const uint4*)(Gb + o1);
            uint4 u2 = *(const uint4*)(Gb + o2);
            uint4 u3 = *(const uint4*)(Gb + o3);
            acc8(s0, u0); acc8(s1, u1); acc8(s2, u2); acc8(s3, u3);
        }
        for (; j + 4 <= m; j += 4) {
            unsigned o0 = ((unsigned)__shfl(idx, j + q) << 8) + lofs;
            uint4 u0 = *(const uint4*)(Gb + o0);
            acc8(s0, u0);
        }
        int rem = m - j;                          // 0..3
        if (rem) {
            int ii = __shfl(idx, j + (q < rem ? q : 0));
            if (q < rem) {
                uint4 u = *(const uint4*)(Gb + (((unsigned)ii << 8) + lofs));
                acc8(s0, u);
            }
        }
    }
    #pragma unroll
    for (int c = 0; c < 8; ++c) s0[c] += s1[c] + s2[c] + s3[c];
    #pragma unroll
    for (int c = 0; c < 8; ++c) {
        s0[c] += __shfl_xor(s0[c], 16);
        s0[c] += __shfl_xor(s0[c], 32);
    }
    uint4 su = *(const uint4*)(Gb + (((unsigned)wid << 8) + lofs));   // self
    acc8(s0, su);
    float d = dis[wid];
    float bb[8];
    *(float4*)&bb[0] = ((const float4*)b1)[hl * 2];
    *(float4*)&bb[4] = ((const float4*)b1)[hl * 2 + 1];
    float o[8];
    #pragma unroll
    for (int c = 0; c < 8; ++c) o[c] = fmaxf(fmaf(s0[c], d, bb[c]), 0.f);
    if (q == 0) {
        uint4 ou;
        ou.x = pack_bf16(o[0], o[1]);
        ou.y = pack_bf16(o[2], o[3]);
        ou.z = pack_bf16(o[4], o[5]);
        ou.w = pack_bf16(o[6], o[7]);
        *(uint4*)((char*)H + (((unsigned)wid << 8) + lofs)) = ou;
    }
}

// ---------------- Aggregation 2: out = dis .* (self+gather) + b2 -------------

__device__ inline void acc4(float* s, uint2 u) {
    float2 t;
    t = unpack_bf16(u.x); s[0] += t.x; s[1] += t.y;
    t = unpack_bf16(u.y); s[2] += t.x; s[3] += t.y;
}

__global__ __launch_bounds__(256) void agg2_kernel(
    const unsigned short* __restrict__ G, const int* __restrict__ row_ptr,
    const int* __restrict__ csr_src, const float* __restrict__ dis,
    const float* __restrict__ b2, float* __restrict__ out, int n) {
    int wid = (blockIdx.x * blockDim.x + threadIdx.x) >> 6;
    int lane = threadIdx.x & 63;
    if (wid >= n) return;
    int q = lane >> 4, hl = lane & 15;
    const char* Gb = (const char*)G;              // row = 128B
    unsigned lofs = (unsigned)(hl << 3);
    float s0[4] = {0,0,0,0}, s1[4] = {0,0,0,0}, s2[4] = {0,0,0,0}, s3[4] = {0,0,0,0};
    int beg = row_ptr[wid], end = row_ptr[wid + 1];
    for (int base = beg; base < end; base += 64) {
        int m = end - base; if (m > 64) m = 64;
        int idx = csr_src[base + (lane < m ? lane : m - 1)];
        int j = 0;
        for (; j + 16 <= m; j += 16) {
            unsigned o0 = ((unsigned)__shfl(idx, j +      q) << 7) + lofs;
            unsigned o1 = ((unsigned)__shfl(idx, j +  4 + q) << 7) + lofs;
            unsigned o2 = ((unsigned)__shfl(idx, j +  8 + q) << 7) + lofs;
            unsigned o3 = ((unsigned)__shfl(idx, j + 12 + q) << 7) + lofs;
            uint2 u0 = *(const uint2*)(Gb + o0);
            uint2 u1 = *(const uint2*)(Gb + o1);
            uint2 u2 = *(const uint2*)(Gb + o2);
            uint2 u3 = *(const uint2*)(Gb + o3);
            acc4(s0, u0); acc4(s1, u1); acc4(s2, u2); acc4(s3, u3);
        }
        for (; j + 4 <= m; j += 4) {
            unsigned o0 = ((unsigned)__shfl(idx, j + q) << 7) + lofs;
            uint2 u0 = *(const uint2*)(Gb + o0);
            acc4(s0, u0);
        }
        int rem = m - j;
        if (rem) {
            int ii = __shfl(idx, j + (q < rem ? q : 0));
            if (q < rem) {
                uint2 u = *(const uint2*)(Gb + (((unsigned)ii << 7) + lofs));
                acc4(s0, u);
            }
        }
    }
    #pragma unroll
    for (int c = 0; c < 4; ++c) s0[c] += s1[c] + s2[c] + s3[c];
    #pragma unroll
    for (int c = 0; c < 4; ++c) {
        s0[c] += __shfl_xor(s0[c], 16);
        s0[c] += __shfl_xor(s0[c], 32);
    }
    uint2 su = *(const uint2*)(Gb + (((unsigned)wid << 7) + lofs));   // self
    acc4(s0, su);
    float d = dis[wid];
    float4 bb = ((const float4*)b2)[hl];
    if (q == 0) {
        float4 o;
        o.x = fmaf(s0[0], d, bb.x);
        o.y = fmaf(s0[1], d, bb.y);
        o.z = fmaf(s0[2], d, bb.z);
        o.w = fmaf(s0[3], d, bb.w);
        ((float4*)out)[(size_t)wid * 16 + hl] = o;
    }
}

// ---------------- launch ----------------

extern "C" void kernel_launch(void* const* d_in, const int* in_sizes, int n_in,
                              void* d_out, int out_size, void* d_ws, size_t ws_size,
                              hipStream_t stream) {
    const float* x  = (const float*)d_in[0];
    const int*   ei = (const int*)d_in[1];
    const float* W1 = (const float*)d_in[2];
    const float* b1 = (const float*)d_in[3];
    const float* W2 = (const float*)d_in[4];
    const float* b2 = (const float*)d_in[5];
    float* out = (float*)d_out;

    int n = in_sizes[0] / IN_CH;       // 100000
    int E = in_sizes[1] / 2;           // 1600000
    const int* srcv = ei;
    const int* dstv = ei + E;

    int NB    = (E + EPB - 1) / EPB;   // 391 edge-blocks
    int NBUCK = (n + 255) >> 8;        // 391 buckets (256 nodes each)
    int L     = NBUCK * NB;
    int nchunks = (L + 1023) / 1024;   // 150

    char* w = (char*)d_ws;
    unsigned short* g1 = (unsigned short*)w;  w += (size_t)n * HID * 2;   // 25.6 MB
    unsigned short* h1 = (unsigned short*)w;  w += (size_t)n * HID * 2;   // 25.6 MB
    unsigned short* g2 = g1;                                              // overlay
    unsigned short* wt1 = (unsigned short*)w; w += (size_t)IN_CH * HID * 2;
    unsigned short* wt2 = (unsigned short*)w; w += (size_t)HID * OUT_CH * 2;
    int*      blockhist = (int*)w; w += (size_t)L * 4;
    int*      flatscan  = (int*)w; w += (size_t)(L + 1) * 4;
    int*      partial   = (int*)w; w += (size_t)1024 * 4;
    unsigned* sorted    = (unsigned*)w; w += (size_t)E * 4;               // 6.4 MB
    int*      csr       = (int*)w; w += (size_t)E * 4;                    // 6.4 MB
    int*      row_ptr   = (int*)w; w += (size_t)(n + 1) * 4;
    float*    dis       = (float*)w; w += (size_t)n * 4;

    bucket_hist<<<NB, 256, 0, stream>>>(dstv, blockhist, W1, wt1, W2, wt2, E, NB, NBUCK);
    scan_partial_kernel<<<nchunks, 1024, 0, stream>>>(blockhist, partial, L);
    scan_topfinal_kernel<<<nchunks, 1024, 0, stream>>>(blockhist, partial, nchunks, flatscan, L);
    bucket_scatter<<<NB, 256, 0, stream>>>(srcv, dstv, flatscan, sorted, E, NB, NBUCK);
    bucket_finalize<<<NBUCK, 256, 0, stream>>>(sorted, flatscan, csr, row_ptr, dis, NB, n);

    gemm1_mfma<<<(n + 127) / 128, 512, 0, stream>>>(x, wt1, dis, g1, n);
    agg1_kernel<<<(n + 3) / 4, 256, 0, stream>>>((const unsigned*)g1, row_ptr, csr, dis, b1, (unsigned*)h1, n);
    gemm2_mfma<<<(n + 255) / 256, 512, 0, stream>>>(h1, wt2, dis, g2, n);
    agg2_kernel<<<(n + 3) / 4, 256, 0, stream>>>(g2, row_ptr, csr, dis, b2, out, n);
}